// Round 9
// baseline (555.759 us; speedup 1.0000x reference)
//
#include <hip/hip_runtime.h>

#define Nn 50000
#define Rr 16
#define Dd 64
#define Fin 128
#define Ee 100000
#define NE (Rr * Ee)     // 1600000
#define NBKT 782         // ceil(Nn/64) buckets (64 rows each)
#define CB 256           // count/place blocks
#define EPB (NE / CB)    // 6250 edges per block (16 blocks per relation)
#define SCTOT (NBKT * CB)  // 200192 count-matrix entries
#define SC_NB (SCTOT / 256)  // 782 scan blocks
#define NTILE (Nn / 16)  // 3125

typedef __attribute__((ext_vector_type(8))) short short8;
typedef __attribute__((ext_vector_type(4))) float f32x4;
typedef unsigned short ushort_t;

__device__ inline ushort_t f2bf(float x) {
  union { float f; unsigned u; } v; v.f = x;
  unsigned u = v.u;
  return (ushort_t)((u + 0x7FFFu + ((u >> 16) & 1u)) >> 16);  // RNE
}
__device__ inline float bf2f(ushort_t h) {
  union { unsigned u; float f; } v; v.u = ((unsigned)h) << 16; return v.f;
}

// ------- fused pre: MFMA init_gemm + convw + LDS-hist bucket count ---------
#define INIT_TILES 3125            // 50000/16
#define INIT_NB 782                // ceil(3125/4)
#define CONVW_NB 512               // 2*16*64*64 / 256
__global__ __launch_bounds__(256) void pre_k(const float* __restrict__ x,
                                             const float* __restrict__ ent,
                                             ushort_t* __restrict__ emb0,
                                             const float* __restrict__ rel,
                                             ushort_t* __restrict__ wbf,
                                             const int* __restrict__ erow,
                                             int* __restrict__ cnt) {
  __shared__ int lh[NBKT];
  int b = blockIdx.x;
  if (b < INIT_NB) {
    int wave = threadIdx.x >> 6, lane = threadIdx.x & 63;
    int nt = lane & 15, quad = lane >> 4;
    int tile = b * 4 + wave;
    if (tile >= INIT_TILES) return;
    const float* xr = x + ((long)tile * 16 + nt) * Fin + quad * 8;
    short8 afrag[4];
#pragma unroll
    for (int ks = 0; ks < 4; ++ks) {
      float4 p0 = *(const float4*)(xr + ks * 32);
      float4 p1 = *(const float4*)(xr + ks * 32 + 4);
      short8 a;
      a[0] = (short)f2bf(p0.x); a[1] = (short)f2bf(p0.y);
      a[2] = (short)f2bf(p0.z); a[3] = (short)f2bf(p0.w);
      a[4] = (short)f2bf(p1.x); a[5] = (short)f2bf(p1.y);
      a[6] = (short)f2bf(p1.z); a[7] = (short)f2bf(p1.w);
      afrag[ks] = a;
    }
    f32x4 acc[4];
#pragma unroll
    for (int dt = 0; dt < 4; ++dt) acc[dt] = (f32x4){0.f, 0.f, 0.f, 0.f};
#pragma unroll
    for (int ks = 0; ks < 4; ++ks) {
#pragma unroll
      for (int dt = 0; dt < 4; ++dt) {
        short8 bfr;
#pragma unroll
        for (int j = 0; j < 8; ++j)
          bfr[j] = (short)f2bf(ent[(unsigned)(ks * 32 + quad * 8 + j) * Dd + dt * 16 + nt]);
        acc[dt] = __builtin_amdgcn_mfma_f32_16x16x32_bf16(afrag[ks], bfr, acc[dt], 0, 0, 0);
      }
    }
#pragma unroll
    for (int dt = 0; dt < 4; ++dt)
#pragma unroll
      for (int reg = 0; reg < 4; ++reg) {
        int row = tile * 16 + quad * 4 + reg;
        emb0[(unsigned)row * Dd + dt * 16 + nt] = f2bf(acc[dt][reg]);
      }
  } else if (b < INIT_NB + CONVW_NB) {
    int i = (b - INIT_NB) * 256 + threadIdx.x;
    wbf[i] = f2bf(rel[i]);
  } else {
    int blk = b - INIT_NB - CONVW_NB;  // 0..CB-1
    int t = threadIdx.x;
    for (int i = t; i < NBKT; i += 256) lh[i] = 0;
    __syncthreads();
    int r = blk >> 4;
    long gbase = (long)r * Ee + (blk & 15) * EPB;
    for (int i = t; i < EPB; i += 256)
      atomicAdd(&lh[erow[gbase + i] >> 6], 1);  // LDS atomics only
    __syncthreads();
    for (int i = t; i < NBKT; i += 256) cnt[i * CB + blk] = lh[i];
  }
}

// ---------------- parallel scan over cnt[200192], bucket-major --------------
__global__ __launch_bounds__(256) void scan1_k(const int* __restrict__ cnt,
                                               int* __restrict__ bsum) {
  __shared__ int ls[256];
  int t = threadIdx.x;
  ls[t] = cnt[blockIdx.x * 256 + t];
  __syncthreads();
  for (int off = 128; off >= 1; off >>= 1) {
    if (t < off) ls[t] += ls[t + off];
    __syncthreads();
  }
  if (t == 0) bsum[blockIdx.x] = ls[0];
}

__global__ __launch_bounds__(1024) void scan2_k(int* __restrict__ bsum) {
  __shared__ int ls[1024];
  int t = threadIdx.x;
  int v = (t < SC_NB) ? bsum[t] : 0;
  ls[t] = v;
  __syncthreads();
  for (int off = 1; off < 1024; off <<= 1) {
    int x = (t >= off) ? ls[t - off] : 0;
    __syncthreads();
    ls[t] += x;
    __syncthreads();
  }
  if (t < SC_NB) bsum[t] = ls[t] - v;  // exclusive
}

__global__ __launch_bounds__(256) void scan3_k(int* __restrict__ cnt,
                                               const int* __restrict__ bsum,
                                               int* __restrict__ cbase,
                                               int* __restrict__ offs) {
  __shared__ int ls[256];
  int t = threadIdx.x, i = blockIdx.x * 256 + t;
  int v = cnt[i];
  ls[t] = v;
  __syncthreads();
  for (int off = 1; off < 256; off <<= 1) {
    int x = (t >= off) ? ls[t - off] : 0;
    __syncthreads();
    ls[t] += x;
    __syncthreads();
  }
  int excl = ls[t] - v + bsum[blockIdx.x];
  cnt[i] = excl;
  if (t == 0) cbase[blockIdx.x] = excl;
  if (i == SCTOT - 1) { cbase[NBKT] = NE; offs[Nn] = NE; }
}

// ------- place: edges -> bucket-grouped ebkt, LDS cursors, block-private ----
__global__ __launch_bounds__(256) void place_k(const int* __restrict__ erow,
                                               const int* __restrict__ ecol,
                                               const float* __restrict__ ev,
                                               const int* __restrict__ base,
                                               uint2* __restrict__ ebkt) {
  __shared__ int lofs[NBKT];
  int blk = blockIdx.x, t = threadIdx.x;
  for (int i = t; i < NBKT; i += 256) lofs[i] = base[i * CB + blk];
  __syncthreads();
  int r = blk >> 4;
  long gbase = (long)r * Ee + (blk & 15) * EPB;
  for (int i = t; i < EPB; i += 256) {
    long idx = gbase + i;
    int row = erow[idx];
    int pos = atomicAdd(&lofs[row >> 6], 1);
    unsigned vb = f2bf(ev[idx]);
    ebkt[pos] = make_uint2(((unsigned)(row & 63) << 4) | (unsigned)r,
                           (vb << 16) | (unsigned)ecol[idx]);
  }
}

// ------- cluster sort: 64-row cluster -> row-contiguous ed2 + offs ---------
__global__ __launch_bounds__(256) void csort_k(const uint2* __restrict__ ebkt,
                                               const int* __restrict__ cbase,
                                               uint2* __restrict__ ed2,
                                               int* __restrict__ offs) {
  __shared__ int lcnt[64], lstart[64], lcur[64];
  int c = blockIdx.x, t = threadIdx.x;
  int s = cbase[c], e = cbase[c + 1];
  if (t < 64) lcnt[t] = 0;
  __syncthreads();
  for (int i = s + t; i < e; i += 256) atomicAdd(&lcnt[ebkt[i].x >> 4], 1);
  __syncthreads();
  if (t == 0) {
    int run = 0;
    for (int rl = 0; rl < 64; ++rl) {
      int cc = lcnt[rl];
      lstart[rl] = run; lcur[rl] = run; run += cc;
    }
  }
  __syncthreads();
  int nrow = Nn - c * 64; if (nrow > 64) nrow = 64;
  if (t < nrow) offs[c * 64 + t] = s + lstart[t];
  for (int i = s + t; i < e; i += 256) {
    uint2 q = ebkt[i];
    int pos = s + atomicAdd(&lcur[q.x >> 4], 1);
    ed2[pos] = make_uint2(q.x & 15u, q.y);
  }
}

// ---- fused_k v3: gather7-shaped (ONE row per wave, 4-wave blocks) + -------
// ---- 4-row in-LDS transform (M=16-padded MFMA, rows 4-15 masked) ----------
// r5 fused lost 2.2x on gather because each wave ran 4 rows SEQUENTIALLY
// (4x the dependent-latency chain); gather7 standalone (1 row/wave) ran 42us.
// v3: block = 4 waves = 4 rows, one per wave (gather7 shape), 8KB swizzled
// Zt strip, one light barrier, then a padded-M transform (4/16 rows used --
// 4x MFMA waste on a ~5% phase). Output rows live in quad==0 lanes.
__global__ __launch_bounds__(256) void fused_k(const ushort_t* __restrict__ emb,
                                               const int* __restrict__ offs,
                                               const uint2* __restrict__ ed2,
                                               const ushort_t* __restrict__ wl,
                                               ushort_t* __restrict__ embout,
                                               float* __restrict__ finout,
                                               int fin) {
  __shared__ ushort_t Zt[4 * 1024];    // 8KB: [row4][rel16 x d64] bf16, swizzled
  __shared__ f32x4 ssred[4];           // per-wave partial row sq-sums (fin)
  const int lane = threadIdx.x & 63;
  const int wave = threadIdx.x >> 6;   // 0..3 == local row
  const int nt = lane & 15, quad = lane >> 4;
  const int qb = quad << 3;
  const ushort_t* embnt = emb + nt;
  char* ztb = (char*)Zt;
  union AW { unsigned w[4]; short8 v; };

  // ---------------- gather: wave owns row = blockIdx*4 + wave ---------------
  {
    const int rl = wave;
    const int row = blockIdx.x * 4 + rl;
    int off_l = (lane < 2) ? offs[row + lane] : 0;
    const int base = __shfl(off_l, 0, 64);
    const int len  = __shfl(off_l, 1, 64) - base;

    f32x4 acc[4];
#pragma unroll
    for (int dt = 0; dt < 4; ++dt) acc[dt] = (f32x4){0.f, 0.f, 0.f, 0.f};

    for (int c = 0; c < len; c += 32) {
      int p = c + (lane & 31);
      uint2 myed = (p < len) ? ed2[base + p] : make_uint2(0u, 0u);  // pad: val=0

      unsigned yw[4][4];  // [dt][pair] packed bf16 pairs for B fragments
      unsigned aw[4];     // packed selector pairs for A fragment
#pragma unroll
      for (int jp = 0; jp < 4; ++jp) {
        unsigned q0 = (unsigned)__shfl((int)myed.y, qb + 2 * jp, 64);
        unsigned q1 = (unsigned)__shfl((int)myed.y, qb + 2 * jp + 1, 64);
        unsigned x0 = (unsigned)__shfl((int)myed.x, qb + 2 * jp, 64);
        unsigned x1 = (unsigned)__shfl((int)myed.x, qb + 2 * jp + 1, 64);
        const ushort_t* e0 = embnt + (q0 & 0xFFFFu) * 64u;
        const ushort_t* e1 = embnt + (q1 & 0xFFFFu) * 64u;
#pragma unroll
        for (int dt = 0; dt < 4; ++dt)
          yw[dt][jp] = (unsigned)e0[dt * 16] | ((unsigned)e1[dt * 16] << 16);
        unsigned t0 = (x0 == (unsigned)nt) ? (q0 >> 16) : 0u;
        unsigned t1 = (x1 == (unsigned)nt) ? (q1 >> 16) : 0u;
        aw[jp] = t0 | (t1 << 16);
      }

      AW af;
      af.w[0] = aw[0]; af.w[1] = aw[1]; af.w[2] = aw[2]; af.w[3] = aw[3];
#pragma unroll
      for (int dt = 0; dt < 4; ++dt) {
        AW bf;
#pragma unroll
        for (int jp = 0; jp < 4; ++jp) bf.w[jp] = yw[dt][jp];
        acc[dt] = __builtin_amdgcn_mfma_f32_16x16x32_bf16(af.v, bf.v, acc[dt], 0, 0, 0);
      }
    }

    // deposit Z-row: D[m=rel=quad*4+reg][n=d=dt*16+nt] -> Zt[rl] swizzled.
    // pair-pack (nt, nt^1) into one 4B word; even-nt lanes store.
    const unsigned swz = (unsigned)((rl & 3) << 4);
    const unsigned rb = (unsigned)(rl * 2048 + quad * 512);
#pragma unroll
    for (int dt = 0; dt < 4; ++dt)
#pragma unroll
      for (int reg = 0; reg < 4; ++reg) {
        unsigned hv = (unsigned)f2bf(acc[dt][reg]);
        unsigned pv = (unsigned)__shfl_xor((int)hv, 1, 64);
        if ((nt & 1) == 0) {
          unsigned lg = rb + (unsigned)(reg * 128 + dt * 32 + nt * 2);
          *(unsigned*)(ztb + (lg ^ swz)) = hv | (pv << 16);
        }
      }
  }
  __syncthreads();

  // ----- transform: wave = out col block; A row m = nt (rows>=4 masked) -----
  const int arow = nt & 3;
  const int abase = arow * 2048;
  const unsigned aswz = (unsigned)(arow << 4);
  const short8 zz = {0, 0, 0, 0, 0, 0, 0, 0};
  f32x4 accO = (f32x4){0.f, 0.f, 0.f, 0.f};
#pragma unroll
  for (int kb = 0; kb < 32; ++kb) {
    short8 af = *(const short8*)(ztb + abase + (((unsigned)(kb * 64 + quad * 16)) ^ aswz));
    if (nt >= 4) af = zz;  // pad rows 4-15 of the M=16 tile
    const ushort_t* bp = wl + (unsigned)((kb >> 1) * 64 + wave * 16 + nt) * 64 +
                         (kb & 1) * 32 + qb;
    short8 bf = *(const short8*)bp;
    accO = __builtin_amdgcn_mfma_f32_16x16x32_bf16(af, bf, accO, 0, 0, 0);
  }

  // D[m=quad*4+reg][n=nt]: m = local row (valid for quad==0); col = wave*16+nt
  if (!fin) {
    if (quad == 0) {
#pragma unroll
      for (int reg = 0; reg < 4; ++reg) {
        int row = blockIdx.x * 4 + reg;
        embout[(unsigned)row * 64u + wave * 16 + nt] = f2bf(fmaxf(accO[reg], 0.f));
      }
    }
    return;
  }

  float v[4];
  if (quad == 0) {
    f32x4 ssq;
#pragma unroll
    for (int reg = 0; reg < 4; ++reg) {
      v[reg] = fmaxf(accO[reg], 0.f);
      ssq[reg] = v[reg] * v[reg];
    }
#pragma unroll
    for (int off = 8; off >= 1; off >>= 1)
#pragma unroll
      for (int reg = 0; reg < 4; ++reg)
        ssq[reg] += __shfl_xor(ssq[reg], off, 64);  // reduce over nt (quad0 only)
    if (nt == 0) ssred[wave] = ssq;
  }
  __syncthreads();
  if (quad == 0) {
    f32x4 t0 = ssred[0], t1 = ssred[1], t2 = ssred[2], t3 = ssred[3];
#pragma unroll
    for (int reg = 0; reg < 4; ++reg) {
      float tot = t0[reg] + t1[reg] + t2[reg] + t3[reg];
      float sc = 1.f / fmaxf(sqrtf(tot), 1e-12f);
      int row = blockIdx.x * 4 + reg;
      finout[(unsigned)row * 64u + wave * 16 + nt] = v[reg] * sc;
    }
  }
}

extern "C" void kernel_launch(void* const* d_in, const int* in_sizes, int n_in,
                              void* d_out, int out_size, void* d_ws, size_t ws_size,
                              hipStream_t stream) {
  const float* x   = (const float*)d_in[0];
  const float* ent = (const float*)d_in[1];
  const float* rel = (const float*)d_in[2];
  const int* erow  = (const int*)d_in[3];
  const int* ecol  = (const int*)d_in[4];
  const float* ev  = (const float*)d_in[5];
  float* out = (float*)d_out;

  char* p = (char*)d_ws;
  ushort_t* emb_a = (ushort_t*)p;  p += (size_t)Nn * Dd * 2;           // 6.4 MB
  ushort_t* emb_b = (ushort_t*)p;  p += (size_t)Nn * Dd * 2;           // 6.4 MB
  ushort_t* wbf   = (ushort_t*)p;  p += (size_t)2 * Rr * Dd * Dd * 2;  // 256 KB
  uint2* ebkt     = (uint2*)p;     p += (size_t)NE * 8;                // 12.8 MB
  uint2* ed2      = (uint2*)p;     p += (size_t)NE * 8;                // 12.8 MB
  int* cnt        = (int*)p;       p += (size_t)SCTOT * 4;             // 0.8 MB
  int* bsum       = (int*)p;       p += (size_t)(SC_NB + 8) * 4;
  int* cbase      = (int*)p;       p += (size_t)(NBKT + 8) * 4;
  int* offs       = (int*)p;       p += (size_t)(Nn + 8) * 4;          // 0.2 MB

  pre_k<<<INIT_NB + CONVW_NB + CB, 256, 0, stream>>>(
      x, ent, emb_a, rel, wbf, erow, cnt);
  scan1_k<<<SC_NB, 256, 0, stream>>>(cnt, bsum);
  scan2_k<<<1, 1024, 0, stream>>>(bsum);
  scan3_k<<<SC_NB, 256, 0, stream>>>(cnt, bsum, cbase, offs);
  place_k<<<CB, 256, 0, stream>>>(erow, ecol, ev, cnt, ebkt);
  csort_k<<<NBKT, 256, 0, stream>>>(ebkt, cbase, ed2, offs);

  // layer 1 (gather + transform fused; gather7-shaped blocks)
  fused_k<<<Nn / 4, 256, 0, stream>>>(emb_a, offs, ed2, wbf, emb_b, nullptr, 0);
  // layer 2 (+ relu + L2 normalize fused)
  fused_k<<<Nn / 4, 256, 0, stream>>>(emb_b, offs, ed2,
                                      wbf + (size_t)Rr * Dd * Dd, nullptr, out, 1);
}

// Round 10
// 445.493 us; speedup vs baseline: 1.2475x; 1.2475x over previous
//
#include <hip/hip_runtime.h>

#define Nn 50000
#define Rr 16
#define Dd 64
#define Fin 128
#define Ee 100000
#define NE (Rr * Ee)     // 1600000
#define NBKT 782         // ceil(Nn/64) buckets (64 rows each)
#define CB 256           // count/place blocks
#define EPB (NE / CB)    // 6250 edges per block (16 blocks per relation)
#define SCTOT (NBKT * CB)  // 200192 count-matrix entries
#define SC_NB (SCTOT / 256)  // 782 scan blocks
#define NTILE (Nn / 16)  // 3125

typedef __attribute__((ext_vector_type(8))) short short8;
typedef __attribute__((ext_vector_type(4))) float f32x4;
typedef unsigned short ushort_t;

__device__ inline ushort_t f2bf(float x) {
  union { float f; unsigned u; } v; v.f = x;
  unsigned u = v.u;
  return (ushort_t)((u + 0x7FFFu + ((u >> 16) & 1u)) >> 16);  // RNE
}
__device__ inline float bf2f(ushort_t h) {
  union { unsigned u; float f; } v; v.u = ((unsigned)h) << 16; return v.f;
}

// ------- fused pre: MFMA init_gemm + convw + LDS-hist bucket count ---------
#define INIT_TILES 3125            // 50000/16
#define INIT_NB 782                // ceil(3125/4)
#define CONVW_NB 512               // 2*16*64*64 / 256
__global__ __launch_bounds__(256) void pre_k(const float* __restrict__ x,
                                             const float* __restrict__ ent,
                                             ushort_t* __restrict__ emb0,
                                             const float* __restrict__ rel,
                                             ushort_t* __restrict__ wbf,
                                             const int* __restrict__ erow,
                                             int* __restrict__ cnt) {
  __shared__ int lh[NBKT];
  int b = blockIdx.x;
  if (b < INIT_NB) {
    int wave = threadIdx.x >> 6, lane = threadIdx.x & 63;
    int nt = lane & 15, quad = lane >> 4;
    int tile = b * 4 + wave;
    if (tile >= INIT_TILES) return;
    const float* xr = x + ((long)tile * 16 + nt) * Fin + quad * 8;
    short8 afrag[4];
#pragma unroll
    for (int ks = 0; ks < 4; ++ks) {
      float4 p0 = *(const float4*)(xr + ks * 32);
      float4 p1 = *(const float4*)(xr + ks * 32 + 4);
      short8 a;
      a[0] = (short)f2bf(p0.x); a[1] = (short)f2bf(p0.y);
      a[2] = (short)f2bf(p0.z); a[3] = (short)f2bf(p0.w);
      a[4] = (short)f2bf(p1.x); a[5] = (short)f2bf(p1.y);
      a[6] = (short)f2bf(p1.z); a[7] = (short)f2bf(p1.w);
      afrag[ks] = a;
    }
    f32x4 acc[4];
#pragma unroll
    for (int dt = 0; dt < 4; ++dt) acc[dt] = (f32x4){0.f, 0.f, 0.f, 0.f};
#pragma unroll
    for (int ks = 0; ks < 4; ++ks) {
#pragma unroll
      for (int dt = 0; dt < 4; ++dt) {
        short8 bfr;
#pragma unroll
        for (int j = 0; j < 8; ++j)
          bfr[j] = (short)f2bf(ent[(unsigned)(ks * 32 + quad * 8 + j) * Dd + dt * 16 + nt]);
        acc[dt] = __builtin_amdgcn_mfma_f32_16x16x32_bf16(afrag[ks], bfr, acc[dt], 0, 0, 0);
      }
    }
#pragma unroll
    for (int dt = 0; dt < 4; ++dt)
#pragma unroll
      for (int reg = 0; reg < 4; ++reg) {
        int row = tile * 16 + quad * 4 + reg;
        emb0[(unsigned)row * Dd + dt * 16 + nt] = f2bf(acc[dt][reg]);
      }
  } else if (b < INIT_NB + CONVW_NB) {
    int i = (b - INIT_NB) * 256 + threadIdx.x;
    wbf[i] = f2bf(rel[i]);
  } else {
    int blk = b - INIT_NB - CONVW_NB;  // 0..CB-1
    int t = threadIdx.x;
    for (int i = t; i < NBKT; i += 256) lh[i] = 0;
    __syncthreads();
    int r = blk >> 4;
    long gbase = (long)r * Ee + (blk & 15) * EPB;
    for (int i = t; i < EPB; i += 256)
      atomicAdd(&lh[erow[gbase + i] >> 6], 1);  // LDS atomics only
    __syncthreads();
    for (int i = t; i < NBKT; i += 256) cnt[i * CB + blk] = lh[i];
  }
}

// ---------------- parallel scan over cnt[200192], bucket-major --------------
__global__ __launch_bounds__(256) void scan1_k(const int* __restrict__ cnt,
                                               int* __restrict__ bsum) {
  __shared__ int ls[256];
  int t = threadIdx.x;
  ls[t] = cnt[blockIdx.x * 256 + t];
  __syncthreads();
  for (int off = 128; off >= 1; off >>= 1) {
    if (t < off) ls[t] += ls[t + off];
    __syncthreads();
  }
  if (t == 0) bsum[blockIdx.x] = ls[0];
}

__global__ __launch_bounds__(1024) void scan2_k(int* __restrict__ bsum) {
  __shared__ int ls[1024];
  int t = threadIdx.x;
  int v = (t < SC_NB) ? bsum[t] : 0;
  ls[t] = v;
  __syncthreads();
  for (int off = 1; off < 1024; off <<= 1) {
    int x = (t >= off) ? ls[t - off] : 0;
    __syncthreads();
    ls[t] += x;
    __syncthreads();
  }
  if (t < SC_NB) bsum[t] = ls[t] - v;  // exclusive
}

__global__ __launch_bounds__(256) void scan3_k(int* __restrict__ cnt,
                                               const int* __restrict__ bsum,
                                               int* __restrict__ cbase,
                                               int* __restrict__ offs) {
  __shared__ int ls[256];
  int t = threadIdx.x, i = blockIdx.x * 256 + t;
  int v = cnt[i];
  ls[t] = v;
  __syncthreads();
  for (int off = 1; off < 256; off <<= 1) {
    int x = (t >= off) ? ls[t - off] : 0;
    __syncthreads();
    ls[t] += x;
    __syncthreads();
  }
  int excl = ls[t] - v + bsum[blockIdx.x];
  cnt[i] = excl;
  if (t == 0) cbase[blockIdx.x] = excl;
  if (i == SCTOT - 1) { cbase[NBKT] = NE; offs[Nn] = NE; }
}

// ------- place: edges -> bucket-grouped ebkt, LDS cursors, block-private ----
__global__ __launch_bounds__(256) void place_k(const int* __restrict__ erow,
                                               const int* __restrict__ ecol,
                                               const float* __restrict__ ev,
                                               const int* __restrict__ base,
                                               uint2* __restrict__ ebkt) {
  __shared__ int lofs[NBKT];
  int blk = blockIdx.x, t = threadIdx.x;
  for (int i = t; i < NBKT; i += 256) lofs[i] = base[i * CB + blk];
  __syncthreads();
  int r = blk >> 4;
  long gbase = (long)r * Ee + (blk & 15) * EPB;
  for (int i = t; i < EPB; i += 256) {
    long idx = gbase + i;
    int row = erow[idx];
    int pos = atomicAdd(&lofs[row >> 6], 1);
    unsigned vb = f2bf(ev[idx]);
    ebkt[pos] = make_uint2(((unsigned)(row & 63) << 4) | (unsigned)r,
                           (vb << 16) | (unsigned)ecol[idx]);
  }
}

// ------- cluster sort: 64-row cluster -> row-contiguous ed2 + offs ---------
__global__ __launch_bounds__(256) void csort_k(const uint2* __restrict__ ebkt,
                                               const int* __restrict__ cbase,
                                               uint2* __restrict__ ed2,
                                               int* __restrict__ offs) {
  __shared__ int lcnt[64], lstart[64], lcur[64];
  int c = blockIdx.x, t = threadIdx.x;
  int s = cbase[c], e = cbase[c + 1];
  if (t < 64) lcnt[t] = 0;
  __syncthreads();
  for (int i = s + t; i < e; i += 256) atomicAdd(&lcnt[ebkt[i].x >> 4], 1);
  __syncthreads();
  if (t == 0) {
    int run = 0;
    for (int rl = 0; rl < 64; ++rl) {
      int cc = lcnt[rl];
      lstart[rl] = run; lcur[rl] = run; run += cc;
    }
  }
  __syncthreads();
  int nrow = Nn - c * 64; if (nrow > 64) nrow = 64;
  if (t < nrow) offs[c * 64 + t] = s + lstart[t];
  for (int i = s + t; i < e; i += 256) {
    uint2 q = ebkt[i];
    int pos = s + atomicAdd(&lcur[q.x >> 4], 1);
    ed2[pos] = make_uint2(q.x & 15u, q.y);
  }
}

// ---- fused_k v4: r5 structure + 2-row INTERLEAVED gather per wave ----------
// r5 (best measured, 97us/layer): wave processes its 4 rows sequentially ->
// one dependent chain (ed2 load -> 16 bpermute -> 32 scattered loads -> MFMA)
// in flight. v4 interleaves rows in PAIRS: both rows' loads issue before
// either row's MFMAs, doubling memory-level parallelism at unchanged
// occupancy (r6 proved wave count is not the lever; MLP is the one untried
// axis). MFMA order per row identical to r5 -> bitwise-identical output.
// Transform phase and deposit layout byte-identical to r5.
__global__ __launch_bounds__(256, 4) void fused_k(const ushort_t* __restrict__ emb,
                                                  const int* __restrict__ offs,
                                                  const uint2* __restrict__ ed2,
                                                  const ushort_t* __restrict__ wl,
                                                  ushort_t* __restrict__ embout,
                                                  float* __restrict__ finout,
                                                  int fin) {
  __shared__ ushort_t Zt[16 * 1024];   // 32KB: [row16][rel16][d64] bf16, swizzled
  __shared__ f32x4 ssred[4][4];        // [wave][quad] row-partial sq-sums (fin)
  const int lane = threadIdx.x & 63;
  const int wave = threadIdx.x >> 6;
  const int nt = lane & 15, quad = lane >> 4;
  const int tile = blockIdx.x;

  const int qb = quad << 3;  // this quad's 8 edge slots / k-offset
  const ushort_t* embnt = emb + nt;
  char* ztb = (char*)Zt;
  union AW { unsigned w[4]; short8 v; };

  // ------- gather: wave owns rows wave*4..+3, processed in 2 pairs ---------
  for (int pr = 0; pr < 2; ++pr) {
    const int rl0 = wave * 4 + pr * 2;       // first row of the pair
    const int row0 = tile * 16 + rl0;
    int off_l = (lane < 3) ? offs[row0 + lane] : 0;
    const int bA = __shfl(off_l, 0, 64);
    const int bB = __shfl(off_l, 1, 64);
    const int eB = __shfl(off_l, 2, 64);
    const int lenA = bB - bA, lenB = eB - bB;
    const int cmax = (lenA > lenB) ? lenA : lenB;

    f32x4 accA[4], accB[4];
#pragma unroll
    for (int dt = 0; dt < 4; ++dt) {
      accA[dt] = (f32x4){0.f, 0.f, 0.f, 0.f};
      accB[dt] = (f32x4){0.f, 0.f, 0.f, 0.f};
    }

    for (int c = 0; c < cmax; c += 32) {
      int p = c + (lane & 31);
      uint2 edA = (p < lenA) ? ed2[bA + p] : make_uint2(0u, 0u);  // pad: val=0
      uint2 edB = (p < lenB) ? ed2[bB + p] : make_uint2(0u, 0u);

      unsigned ywA[4][4], awA[4], ywB[4][4], awB[4];
#pragma unroll
      for (int jp = 0; jp < 4; ++jp) {   // row A: issue all loads first
        unsigned q0 = (unsigned)__shfl((int)edA.y, qb + 2 * jp, 64);
        unsigned q1 = (unsigned)__shfl((int)edA.y, qb + 2 * jp + 1, 64);
        unsigned x0 = (unsigned)__shfl((int)edA.x, qb + 2 * jp, 64);
        unsigned x1 = (unsigned)__shfl((int)edA.x, qb + 2 * jp + 1, 64);
        const ushort_t* e0 = embnt + (q0 & 0xFFFFu) * 64u;
        const ushort_t* e1 = embnt + (q1 & 0xFFFFu) * 64u;
#pragma unroll
        for (int dt = 0; dt < 4; ++dt)
          ywA[dt][jp] = (unsigned)e0[dt * 16] | ((unsigned)e1[dt * 16] << 16);
        unsigned t0 = (x0 == (unsigned)nt) ? (q0 >> 16) : 0u;
        unsigned t1 = (x1 == (unsigned)nt) ? (q1 >> 16) : 0u;
        awA[jp] = t0 | (t1 << 16);
      }
#pragma unroll
      for (int jp = 0; jp < 4; ++jp) {   // row B: loads overlap row A's latency
        unsigned q0 = (unsigned)__shfl((int)edB.y, qb + 2 * jp, 64);
        unsigned q1 = (unsigned)__shfl((int)edB.y, qb + 2 * jp + 1, 64);
        unsigned x0 = (unsigned)__shfl((int)edB.x, qb + 2 * jp, 64);
        unsigned x1 = (unsigned)__shfl((int)edB.x, qb + 2 * jp + 1, 64);
        const ushort_t* e0 = embnt + (q0 & 0xFFFFu) * 64u;
        const ushort_t* e1 = embnt + (q1 & 0xFFFFu) * 64u;
#pragma unroll
        for (int dt = 0; dt < 4; ++dt)
          ywB[dt][jp] = (unsigned)e0[dt * 16] | ((unsigned)e1[dt * 16] << 16);
        unsigned t0 = (x0 == (unsigned)nt) ? (q0 >> 16) : 0u;
        unsigned t1 = (x1 == (unsigned)nt) ? (q1 >> 16) : 0u;
        awB[jp] = t0 | (t1 << 16);
      }

      AW afA;
      afA.w[0] = awA[0]; afA.w[1] = awA[1]; afA.w[2] = awA[2]; afA.w[3] = awA[3];
#pragma unroll
      for (int dt = 0; dt < 4; ++dt) {
        AW bf;
#pragma unroll
        for (int jp = 0; jp < 4; ++jp) bf.w[jp] = ywA[dt][jp];
        accA[dt] = __builtin_amdgcn_mfma_f32_16x16x32_bf16(afA.v, bf.v, accA[dt], 0, 0, 0);
      }
      AW afB;
      afB.w[0] = awB[0]; afB.w[1] = awB[1]; afB.w[2] = awB[2]; afB.w[3] = awB[3];
#pragma unroll
      for (int dt = 0; dt < 4; ++dt) {
        AW bf;
#pragma unroll
        for (int jp = 0; jp < 4; ++jp) bf.w[jp] = ywB[dt][jp];
        accB[dt] = __builtin_amdgcn_mfma_f32_16x16x32_bf16(afB.v, bf.v, accB[dt], 0, 0, 0);
      }
    }

    // deposit both rows: D[m=rel=quad*4+reg][n=d=dt*16+nt] -> Zt swizzled.
#pragma unroll
    for (int h = 0; h < 2; ++h) {
      const int rl = rl0 + h;
      const unsigned swz = (unsigned)((rl & 7) << 4);
      const unsigned rb = (unsigned)(rl * 2048 + quad * 512);
#pragma unroll
      for (int dt = 0; dt < 4; ++dt)
#pragma unroll
        for (int reg = 0; reg < 4; ++reg) {
          float av = h ? accB[dt][reg] : accA[dt][reg];  // h is unrolled: static
          unsigned hv = (unsigned)f2bf(av);
          unsigned pv = (unsigned)__shfl_xor((int)hv, 1, 64);
          if ((nt & 1) == 0) {
            unsigned lg = rb + (unsigned)(reg * 128 + dt * 32 + nt * 2);
            *(unsigned*)(ztb + (lg ^ swz)) = hv | (pv << 16);
          }
        }
    }
  }
  __syncthreads();

  // ------------- transform phase: wave = dt quadrant (cols wave*16..+15) ----
  const int s0 = nt * 2048 + (((quad    ) ^ (nt & 7)) << 4);
  const int s1 = nt * 2048 + (((quad + 4) ^ (nt & 7)) << 4);
  f32x4 tA = (f32x4){0.f, 0.f, 0.f, 0.f};
  f32x4 tB = (f32x4){0.f, 0.f, 0.f, 0.f};
#pragma unroll
  for (int r = 0; r < 16; r += 2) {
    const char* ab0 = ztb + r * 128;
    const char* ab1 = ztb + (r + 1) * 128;
    short8 a00 = *(const short8*)(ab0 + s0);
    short8 a01 = *(const short8*)(ab0 + s1);
    short8 a10 = *(const short8*)(ab1 + s0);
    short8 a11 = *(const short8*)(ab1 + s1);
    const ushort_t* bp0 = wl + (unsigned)(r * Dd + wave * 16 + nt) * Dd + qb;
    const ushort_t* bp1 = wl + (unsigned)((r + 1) * Dd + wave * 16 + nt) * Dd + qb;
    short8 b00 = *(const short8*)(bp0);
    short8 b01 = *(const short8*)(bp0 + 32);
    short8 b10 = *(const short8*)(bp1);
    short8 b11 = *(const short8*)(bp1 + 32);
    tA = __builtin_amdgcn_mfma_f32_16x16x32_bf16(a00, b00, tA, 0, 0, 0);
    tA = __builtin_amdgcn_mfma_f32_16x16x32_bf16(a01, b01, tA, 0, 0, 0);
    tB = __builtin_amdgcn_mfma_f32_16x16x32_bf16(a10, b10, tB, 0, 0, 0);
    tB = __builtin_amdgcn_mfma_f32_16x16x32_bf16(a11, b11, tB, 0, 0, 0);
  }
  f32x4 accO;
#pragma unroll
  for (int reg = 0; reg < 4; ++reg) accO[reg] = tA[reg] + tB[reg];

  // D[m=quad*4+reg = row][n=nt]: out col = wave*16+nt
  if (!fin) {
#pragma unroll
    for (int reg = 0; reg < 4; ++reg) {
      int row = tile * 16 + quad * 4 + reg;
      embout[(unsigned)row * 64u + wave * 16 + nt] = f2bf(fmaxf(accO[reg], 0.f));
    }
  } else {
    float v[4];
    f32x4 ssq;
#pragma unroll
    for (int reg = 0; reg < 4; ++reg) {
      v[reg] = fmaxf(accO[reg], 0.f);
      ssq[reg] = v[reg] * v[reg];
    }
#pragma unroll
    for (int off = 8; off >= 1; off >>= 1)
#pragma unroll
      for (int reg = 0; reg < 4; ++reg)
        ssq[reg] += __shfl_xor(ssq[reg], off, 64);  // reduce over nt bits
    if (nt == 0) ssred[wave][quad] = ssq;
    __syncthreads();
    f32x4 t0 = ssred[0][quad], t1 = ssred[1][quad];
    f32x4 t2 = ssred[2][quad], t3 = ssred[3][quad];
#pragma unroll
    for (int reg = 0; reg < 4; ++reg) {
      float tot = t0[reg] + t1[reg] + t2[reg] + t3[reg];
      float sc = 1.f / fmaxf(sqrtf(tot), 1e-12f);
      int row = tile * 16 + quad * 4 + reg;
      finout[(unsigned)row * 64u + wave * 16 + nt] = v[reg] * sc;
    }
  }
}

extern "C" void kernel_launch(void* const* d_in, const int* in_sizes, int n_in,
                              void* d_out, int out_size, void* d_ws, size_t ws_size,
                              hipStream_t stream) {
  const float* x   = (const float*)d_in[0];
  const float* ent = (const float*)d_in[1];
  const float* rel = (const float*)d_in[2];
  const int* erow  = (const int*)d_in[3];
  const int* ecol  = (const int*)d_in[4];
  const float* ev  = (const float*)d_in[5];
  float* out = (float*)d_out;

  char* p = (char*)d_ws;
  ushort_t* emb_a = (ushort_t*)p;  p += (size_t)Nn * Dd * 2;           // 6.4 MB
  ushort_t* emb_b = (ushort_t*)p;  p += (size_t)Nn * Dd * 2;           // 6.4 MB
  ushort_t* wbf   = (ushort_t*)p;  p += (size_t)2 * Rr * Dd * Dd * 2;  // 256 KB
  uint2* ebkt     = (uint2*)p;     p += (size_t)NE * 8;                // 12.8 MB
  uint2* ed2      = (uint2*)p;     p += (size_t)NE * 8;                // 12.8 MB
  int* cnt        = (int*)p;       p += (size_t)SCTOT * 4;             // 0.8 MB
  int* bsum       = (int*)p;       p += (size_t)(SC_NB + 8) * 4;
  int* cbase      = (int*)p;       p += (size_t)(NBKT + 8) * 4;
  int* offs       = (int*)p;       p += (size_t)(Nn + 8) * 4;          // 0.2 MB

  pre_k<<<INIT_NB + CONVW_NB + CB, 256, 0, stream>>>(
      x, ent, emb_a, rel, wbf, erow, cnt);
  scan1_k<<<SC_NB, 256, 0, stream>>>(cnt, bsum);
  scan2_k<<<1, 1024, 0, stream>>>(bsum);
  scan3_k<<<SC_NB, 256, 0, stream>>>(cnt, bsum, cbase, offs);
  place_k<<<CB, 256, 0, stream>>>(erow, ecol, ev, cnt, ebkt);
  csort_k<<<NBKT, 256, 0, stream>>>(ebkt, cbase, ed2, offs);

  // layer 1 (gather + transform fused; pair-interleaved gather)
  fused_k<<<NTILE, 256, 0, stream>>>(emb_a, offs, ed2, wbf, emb_b, nullptr, 0);
  // layer 2 (+ relu + L2 normalize fused)
  fused_k<<<NTILE, 256, 0, stream>>>(emb_b, offs, ed2,
                                     wbf + (size_t)Rr * Dd * Dd, nullptr, out, 1);
}

// Round 11
// 320.914 us; speedup vs baseline: 1.7318x; 1.3882x over previous
//
#include <hip/hip_runtime.h>

#define Nn 50000
#define Rr 16
#define Dd 64
#define Fin 128
#define Ee 100000
#define NE (Rr * Ee)     // 1600000
#define NBKT 782         // ceil(Nn/64) buckets (64 rows each)
#define CB 256           // count/place blocks
#define EPB (NE / CB)    // 6250 edges per block (16 blocks per relation)
#define SCTOT (NBKT * CB)  // 200192 count-matrix entries
#define SC_NB (SCTOT / 256)  // 782 scan blocks
#define NTILE (Nn / 16)  // 3125

typedef __attribute__((ext_vector_type(8))) short short8;
typedef __attribute__((ext_vector_type(4))) float f32x4;
typedef unsigned short ushort_t;

__device__ inline ushort_t f2bf(float x) {
  union { float f; unsigned u; } v; v.f = x;
  unsigned u = v.u;
  return (ushort_t)((u + 0x7FFFu + ((u >> 16) & 1u)) >> 16);  // RNE
}
__device__ inline float bf2f(ushort_t h) {
  union { unsigned u; float f; } v; v.u = ((unsigned)h) << 16; return v.f;
}

// ------- fused pre: MFMA init_gemm + convw + LDS-hist bucket count ---------
#define INIT_TILES 3125            // 50000/16
#define INIT_NB 782                // ceil(3125/4)
#define CONVW_NB 512               // 2*16*64*64 / 256
__global__ __launch_bounds__(256) void pre_k(const float* __restrict__ x,
                                             const float* __restrict__ ent,
                                             ushort_t* __restrict__ emb0,
                                             const float* __restrict__ rel,
                                             ushort_t* __restrict__ wbf,
                                             const int* __restrict__ erow,
                                             int* __restrict__ cnt) {
  __shared__ int lh[NBKT];
  int b = blockIdx.x;
  if (b < INIT_NB) {
    int wave = threadIdx.x >> 6, lane = threadIdx.x & 63;
    int nt = lane & 15, quad = lane >> 4;
    int tile = b * 4 + wave;
    if (tile >= INIT_TILES) return;
    const float* xr = x + ((long)tile * 16 + nt) * Fin + quad * 8;
    short8 afrag[4];
#pragma unroll
    for (int ks = 0; ks < 4; ++ks) {
      float4 p0 = *(const float4*)(xr + ks * 32);
      float4 p1 = *(const float4*)(xr + ks * 32 + 4);
      short8 a;
      a[0] = (short)f2bf(p0.x); a[1] = (short)f2bf(p0.y);
      a[2] = (short)f2bf(p0.z); a[3] = (short)f2bf(p0.w);
      a[4] = (short)f2bf(p1.x); a[5] = (short)f2bf(p1.y);
      a[6] = (short)f2bf(p1.z); a[7] = (short)f2bf(p1.w);
      afrag[ks] = a;
    }
    f32x4 acc[4];
#pragma unroll
    for (int dt = 0; dt < 4; ++dt) acc[dt] = (f32x4){0.f, 0.f, 0.f, 0.f};
#pragma unroll
    for (int ks = 0; ks < 4; ++ks) {
#pragma unroll
      for (int dt = 0; dt < 4; ++dt) {
        short8 bfr;
#pragma unroll
        for (int j = 0; j < 8; ++j)
          bfr[j] = (short)f2bf(ent[(unsigned)(ks * 32 + quad * 8 + j) * Dd + dt * 16 + nt]);
        acc[dt] = __builtin_amdgcn_mfma_f32_16x16x32_bf16(afrag[ks], bfr, acc[dt], 0, 0, 0);
      }
    }
#pragma unroll
    for (int dt = 0; dt < 4; ++dt)
#pragma unroll
      for (int reg = 0; reg < 4; ++reg) {
        int row = tile * 16 + quad * 4 + reg;
        emb0[(unsigned)row * Dd + dt * 16 + nt] = f2bf(acc[dt][reg]);
      }
  } else if (b < INIT_NB + CONVW_NB) {
    int i = (b - INIT_NB) * 256 + threadIdx.x;
    wbf[i] = f2bf(rel[i]);
  } else {
    int blk = b - INIT_NB - CONVW_NB;  // 0..CB-1
    int t = threadIdx.x;
    for (int i = t; i < NBKT; i += 256) lh[i] = 0;
    __syncthreads();
    int r = blk >> 4;
    long gbase = (long)r * Ee + (blk & 15) * EPB;
    for (int i = t; i < EPB; i += 256)
      atomicAdd(&lh[erow[gbase + i] >> 6], 1);  // LDS atomics only
    __syncthreads();
    for (int i = t; i < NBKT; i += 256) cnt[i * CB + blk] = lh[i];
  }
}

// ---------------- parallel scan over cnt[200192], bucket-major --------------
__global__ __launch_bounds__(256) void scan1_k(const int* __restrict__ cnt,
                                               int* __restrict__ bsum) {
  __shared__ int ls[256];
  int t = threadIdx.x;
  ls[t] = cnt[blockIdx.x * 256 + t];
  __syncthreads();
  for (int off = 128; off >= 1; off >>= 1) {
    if (t < off) ls[t] += ls[t + off];
    __syncthreads();
  }
  if (t == 0) bsum[blockIdx.x] = ls[0];
}

__global__ __launch_bounds__(1024) void scan2_k(int* __restrict__ bsum) {
  __shared__ int ls[1024];
  int t = threadIdx.x;
  int v = (t < SC_NB) ? bsum[t] : 0;
  ls[t] = v;
  __syncthreads();
  for (int off = 1; off < 1024; off <<= 1) {
    int x = (t >= off) ? ls[t - off] : 0;
    __syncthreads();
    ls[t] += x;
    __syncthreads();
  }
  if (t < SC_NB) bsum[t] = ls[t] - v;  // exclusive
}

__global__ __launch_bounds__(256) void scan3_k(int* __restrict__ cnt,
                                               const int* __restrict__ bsum,
                                               int* __restrict__ cbase,
                                               int* __restrict__ offs) {
  __shared__ int ls[256];
  int t = threadIdx.x, i = blockIdx.x * 256 + t;
  int v = cnt[i];
  ls[t] = v;
  __syncthreads();
  for (int off = 1; off < 256; off <<= 1) {
    int x = (t >= off) ? ls[t - off] : 0;
    __syncthreads();
    ls[t] += x;
    __syncthreads();
  }
  int excl = ls[t] - v + bsum[blockIdx.x];
  cnt[i] = excl;
  if (t == 0) cbase[blockIdx.x] = excl;
  if (i == SCTOT - 1) { cbase[NBKT] = NE; offs[Nn] = NE; }
}

// ------- place: edges -> bucket-grouped ebkt, LDS cursors, block-private ----
__global__ __launch_bounds__(256) void place_k(const int* __restrict__ erow,
                                               const int* __restrict__ ecol,
                                               const float* __restrict__ ev,
                                               const int* __restrict__ base,
                                               uint2* __restrict__ ebkt) {
  __shared__ int lofs[NBKT];
  int blk = blockIdx.x, t = threadIdx.x;
  for (int i = t; i < NBKT; i += 256) lofs[i] = base[i * CB + blk];
  __syncthreads();
  int r = blk >> 4;
  long gbase = (long)r * Ee + (blk & 15) * EPB;
  for (int i = t; i < EPB; i += 256) {
    long idx = gbase + i;
    int row = erow[idx];
    int pos = atomicAdd(&lofs[row >> 6], 1);
    unsigned vb = f2bf(ev[idx]);
    ebkt[pos] = make_uint2(((unsigned)(row & 63) << 4) | (unsigned)r,
                           (vb << 16) | (unsigned)ecol[idx]);
  }
}

// ------- cluster sort: 64-row cluster -> row-contiguous ed2 + offs ---------
__global__ __launch_bounds__(256) void csort_k(const uint2* __restrict__ ebkt,
                                               const int* __restrict__ cbase,
                                               uint2* __restrict__ ed2,
                                               int* __restrict__ offs) {
  __shared__ int lcnt[64], lstart[64], lcur[64];
  int c = blockIdx.x, t = threadIdx.x;
  int s = cbase[c], e = cbase[c + 1];
  if (t < 64) lcnt[t] = 0;
  __syncthreads();
  for (int i = s + t; i < e; i += 256) atomicAdd(&lcnt[ebkt[i].x >> 4], 1);
  __syncthreads();
  if (t == 0) {
    int run = 0;
    for (int rl = 0; rl < 64; ++rl) {
      int cc = lcnt[rl];
      lstart[rl] = run; lcur[rl] = run; run += cc;
    }
  }
  __syncthreads();
  int nrow = Nn - c * 64; if (nrow > 64) nrow = 64;
  if (t < nrow) offs[c * 64 + t] = s + lstart[t];
  for (int i = s + t; i < e; i += 256) {
    uint2 q = ebkt[i];
    int pos = s + atomicAdd(&lcur[q.x >> 4], 1);
    ed2[pos] = make_uint2(q.x & 15u, q.y);
  }
}

// ---- fused_k (r5 structure, session best 330us) + 2 local fixes -----------
// (1) deposit bank fix: old store bank = dt*8+nt/2, independent of writer
//     quad (512B stride == 0 mod 32 banks) -> 4-way conflict on all 16
//     stores/row (3.2M conflict cycles). Extend the XOR swizzle with
//     ((rel&7)<<4): bank gains ^((rel&7)<<2) -> 2 lanes/bank = free.
//     Read side applies the identical involution (^(r&7) term, r = rel).
// (2) s_setprio(1) around the gather MFMA cluster: gather waves are
//     barrier-free/independent here (the regime where setprio measured
//     +4-7%, unlike lockstep GEMM where it is null).
__global__ __launch_bounds__(256) void fused_k(const ushort_t* __restrict__ emb,
                                               const int* __restrict__ offs,
                                               const uint2* __restrict__ ed2,
                                               const ushort_t* __restrict__ wl,
                                               ushort_t* __restrict__ embout,
                                               float* __restrict__ finout,
                                               int fin) {
  __shared__ ushort_t Zt[16 * 1024];   // 32KB: [row16][rel16][d64] bf16, swizzled
  __shared__ f32x4 ssred[4][4];        // [wave][quad] row-partial sq-sums (fin)
  const int lane = threadIdx.x & 63;
  const int wave = threadIdx.x >> 6;
  const int nt = lane & 15, quad = lane >> 4;
  const int tile = blockIdx.x;

  const int qb = quad << 3;  // this quad's 8 edge slots / k-offset
  const ushort_t* embnt = emb + nt;
  char* ztb = (char*)Zt;
  union AW { unsigned w[4]; short8 v; };

  // ---------------- gather phase: wave owns rows wave*4 .. wave*4+3 ---------
  for (int rr = 0; rr < 4; ++rr) {
    const int rl = wave * 4 + rr;          // row_local 0..15
    const int row = tile * 16 + rl;
    int off_l = (lane < 2) ? offs[row + lane] : 0;
    const int base = __shfl(off_l, 0, 64);
    const int len  = __shfl(off_l, 1, 64) - base;

    f32x4 acc[4];
#pragma unroll
    for (int dt = 0; dt < 4; ++dt) acc[dt] = (f32x4){0.f, 0.f, 0.f, 0.f};

    for (int c = 0; c < len; c += 32) {
      int p = c + (lane & 31);
      uint2 myed = (p < len) ? ed2[base + p] : make_uint2(0u, 0u);  // pad: val=0

      unsigned yw[4][4];  // [dt][pair] packed bf16 pairs for B fragments
      unsigned aw[4];     // packed selector pairs for A fragment
#pragma unroll
      for (int jp = 0; jp < 4; ++jp) {
        unsigned q0 = (unsigned)__shfl((int)myed.y, qb + 2 * jp, 64);
        unsigned q1 = (unsigned)__shfl((int)myed.y, qb + 2 * jp + 1, 64);
        unsigned x0 = (unsigned)__shfl((int)myed.x, qb + 2 * jp, 64);
        unsigned x1 = (unsigned)__shfl((int)myed.x, qb + 2 * jp + 1, 64);
        const ushort_t* e0 = embnt + (q0 & 0xFFFFu) * 64u;
        const ushort_t* e1 = embnt + (q1 & 0xFFFFu) * 64u;
#pragma unroll
        for (int dt = 0; dt < 4; ++dt)
          yw[dt][jp] = (unsigned)e0[dt * 16] | ((unsigned)e1[dt * 16] << 16);
        unsigned t0 = (x0 == (unsigned)nt) ? (q0 >> 16) : 0u;
        unsigned t1 = (x1 == (unsigned)nt) ? (q1 >> 16) : 0u;
        aw[jp] = t0 | (t1 << 16);
      }

      AW af;
      af.w[0] = aw[0]; af.w[1] = aw[1]; af.w[2] = aw[2]; af.w[3] = aw[3];
      __builtin_amdgcn_s_setprio(1);
#pragma unroll
      for (int dt = 0; dt < 4; ++dt) {
        AW bf;
#pragma unroll
        for (int jp = 0; jp < 4; ++jp) bf.w[jp] = yw[dt][jp];
        acc[dt] = __builtin_amdgcn_mfma_f32_16x16x32_bf16(af.v, bf.v, acc[dt], 0, 0, 0);
      }
      __builtin_amdgcn_s_setprio(0);
    }

    // deposit Z-row: D[m=rel=quad*4+reg][n=d=dt*16+nt] -> Zt swizzled.
    // byte(rl,rel,d) = rl*2048 + rel*128 + (d*2 ^ ((rel&7)<<4) ^ ((rl&7)<<4))
    // pair-pack (nt, nt^1) into one 4B word; even-nt lanes store.
    const unsigned rlsw = (unsigned)((rl & 7) << 4);
    const unsigned rb = (unsigned)(rl * 2048 + quad * 512);
#pragma unroll
    for (int dt = 0; dt < 4; ++dt)
#pragma unroll
      for (int reg = 0; reg < 4; ++reg) {
        unsigned hv = (unsigned)f2bf(acc[dt][reg]);
        unsigned pv = (unsigned)__shfl_xor((int)hv, 1, 64);
        if ((nt & 1) == 0) {
          unsigned relsw = (unsigned)((((quad << 2) + reg) & 7) << 4);
          unsigned lg = rb + (unsigned)(reg * 128) +
                        (((unsigned)(dt * 32 + nt * 2)) ^ relsw ^ rlsw);
          *(unsigned*)(ztb + lg) = hv | (pv << 16);
        }
      }
  }
  __syncthreads();

  // ------------- transform phase: wave = dt quadrant (cols wave*16..+15) ----
  const int sbase = nt * 2048;
  const int sx = quad ^ (nt & 7);
  f32x4 accA = (f32x4){0.f, 0.f, 0.f, 0.f};
  f32x4 accB = (f32x4){0.f, 0.f, 0.f, 0.f};
#pragma unroll
  for (int r = 0; r < 16; r += 2) {
    const char* ab0 = ztb + sbase + r * 128;
    const char* ab1 = ztb + sbase + (r + 1) * 128;
    const int o0 = (sx ^ (r & 7)) << 4;
    const int o1 = (sx ^ ((r + 1) & 7)) << 4;
    short8 a00 = *(const short8*)(ab0 + o0);
    short8 a01 = *(const short8*)(ab0 + (o0 ^ 64));
    short8 a10 = *(const short8*)(ab1 + o1);
    short8 a11 = *(const short8*)(ab1 + (o1 ^ 64));
    const ushort_t* bp0 = wl + (unsigned)(r * Dd + wave * 16 + nt) * Dd + qb;
    const ushort_t* bp1 = wl + (unsigned)((r + 1) * Dd + wave * 16 + nt) * Dd + qb;
    short8 b00 = *(const short8*)(bp0);
    short8 b01 = *(const short8*)(bp0 + 32);
    short8 b10 = *(const short8*)(bp1);
    short8 b11 = *(const short8*)(bp1 + 32);
    accA = __builtin_amdgcn_mfma_f32_16x16x32_bf16(a00, b00, accA, 0, 0, 0);
    accA = __builtin_amdgcn_mfma_f32_16x16x32_bf16(a01, b01, accA, 0, 0, 0);
    accB = __builtin_amdgcn_mfma_f32_16x16x32_bf16(a10, b10, accB, 0, 0, 0);
    accB = __builtin_amdgcn_mfma_f32_16x16x32_bf16(a11, b11, accB, 0, 0, 0);
  }
  f32x4 accO;
#pragma unroll
  for (int reg = 0; reg < 4; ++reg) accO[reg] = accA[reg] + accB[reg];

  // D[m=quad*4+reg = row][n=nt]: out col = wave*16+nt
  if (!fin) {
#pragma unroll
    for (int reg = 0; reg < 4; ++reg) {
      int row = tile * 16 + quad * 4 + reg;
      embout[(unsigned)row * 64u + wave * 16 + nt] = f2bf(fmaxf(accO[reg], 0.f));
    }
  } else {
    float v[4];
    f32x4 ssq;
#pragma unroll
    for (int reg = 0; reg < 4; ++reg) {
      v[reg] = fmaxf(accO[reg], 0.f);
      ssq[reg] = v[reg] * v[reg];
    }
#pragma unroll
    for (int off = 8; off >= 1; off >>= 1)
#pragma unroll
      for (int reg = 0; reg < 4; ++reg)
        ssq[reg] += __shfl_xor(ssq[reg], off, 64);  // reduce over nt bits
    if (nt == 0) ssred[wave][quad] = ssq;
    __syncthreads();
    f32x4 t0 = ssred[0][quad], t1 = ssred[1][quad];
    f32x4 t2 = ssred[2][quad], t3 = ssred[3][quad];
#pragma unroll
    for (int reg = 0; reg < 4; ++reg) {
      float tot = t0[reg] + t1[reg] + t2[reg] + t3[reg];
      float sc = 1.f / fmaxf(sqrtf(tot), 1e-12f);
      int row = tile * 16 + quad * 4 + reg;
      finout[(unsigned)row * 64u + wave * 16 + nt] = v[reg] * sc;
    }
  }
}

extern "C" void kernel_launch(void* const* d_in, const int* in_sizes, int n_in,
                              void* d_out, int out_size, void* d_ws, size_t ws_size,
                              hipStream_t stream) {
  const float* x   = (const float*)d_in[0];
  const float* ent = (const float*)d_in[1];
  const float* rel = (const float*)d_in[2];
  const int* erow  = (const int*)d_in[3];
  const int* ecol  = (const int*)d_in[4];
  const float* ev  = (const float*)d_in[5];
  float* out = (float*)d_out;

  char* p = (char*)d_ws;
  ushort_t* emb_a = (ushort_t*)p;  p += (size_t)Nn * Dd * 2;           // 6.4 MB
  ushort_t* emb_b = (ushort_t*)p;  p += (size_t)Nn * Dd * 2;           // 6.4 MB
  ushort_t* wbf   = (ushort_t*)p;  p += (size_t)2 * Rr * Dd * Dd * 2;  // 256 KB
  uint2* ebkt     = (uint2*)p;     p += (size_t)NE * 8;                // 12.8 MB
  uint2* ed2      = (uint2*)p;     p += (size_t)NE * 8;                // 12.8 MB
  int* cnt        = (int*)p;       p += (size_t)SCTOT * 4;             // 0.8 MB
  int* bsum       = (int*)p;       p += (size_t)(SC_NB + 8) * 4;
  int* cbase      = (int*)p;       p += (size_t)(NBKT + 8) * 4;
  int* offs       = (int*)p;       p += (size_t)(Nn + 8) * 4;          // 0.2 MB

  pre_k<<<INIT_NB + CONVW_NB + CB, 256, 0, stream>>>(
      x, ent, emb_a, rel, wbf, erow, cnt);
  scan1_k<<<SC_NB, 256, 0, stream>>>(cnt, bsum);
  scan2_k<<<1, 1024, 0, stream>>>(bsum);
  scan3_k<<<SC_NB, 256, 0, stream>>>(cnt, bsum, cbase, offs);
  place_k<<<CB, 256, 0, stream>>>(erow, ecol, ev, cnt, ebkt);
  csort_k<<<NBKT, 256, 0, stream>>>(ebkt, cbase, ed2, offs);

  // layer 1 (gather + transform fused; no Z round-trip)
  fused_k<<<NTILE, 256, 0, stream>>>(emb_a, offs, ed2, wbf, emb_b, nullptr, 0);
  // layer 2 (+ relu + L2 normalize fused)
  fused_k<<<NTILE, 256, 0, stream>>>(emb_b, offs, ed2,
                                     wbf + (size_t)Rr * Dd * Dd, nullptr, out, 1);
}